// Round 10
// baseline (34.607 us; speedup 1.0000x reference)
//
#include <hip/hip_runtime.h>

#define Bt 32768
#define Dt 64
#define St 16
#define Ht 128
#define At 17

typedef __attribute__((ext_vector_type(8))) short bf16x8;
typedef __attribute__((ext_vector_type(4))) float f32x4;

// ---- workspace layout (bytes) ----
#define CNT_OFF   0          // int[16*16] -- 64B padding per skill (atomic spread)
#define PERM_OFF  1024       // u16 [S][B]  (1 MiB)
#define WB_OFF    1049600    // bf16 transposed weight images [n][k], XOR-swizzled
#define OA1 0        // Wa1^T: 128 rows x 128B (K=64)
#define OA2 16384    // Wa2^T: 128 rows x 256B (K=128)
#define OA3 49152    // Wa3^T: 32-row region, rows >=17 unused garbage
#define OC1 57344    // Wc1^T
#define OC2 73728    // Wc2^T
#define SKB 106496   // per-skill stride

__device__ __forceinline__ unsigned short f2bf(float f) {
  union { float f; unsigned u; } v; v.f = f;
  unsigned r = v.u + 0x7FFFu + ((v.u >> 16) & 1u);  // RNE
  return (unsigned short)(r >> 16);
}

__device__ __forceinline__ unsigned cvtpk(float a, float b) {
  unsigned r;
  asm("v_cvt_pk_bf16_f32 %0, %1, %2" : "=v"(r) : "v"(a), "v"(b));
  return r;
}

// tanh(acc + bias) with b2 = 2*bias precomputed
__device__ __forceinline__ float tanh_fb(float acc, float b2) {
  const float t = __expf(__builtin_fmaf(acc, 2.0f, b2));  // inf-safe
  const float r = __builtin_amdgcn_rcpf(t + 1.0f);
  return __builtin_fmaf(-2.0f, r, 1.0f);
}

__device__ __forceinline__ f32x4 MFMA(bf16x8 a, bf16x8 b, f32x4 c) {
  return __builtin_amdgcn_mfma_f32_16x16x32_bf16(a, b, c, 0, 0, 0);
}

#define LGKM0() asm volatile("s_waitcnt lgkmcnt(0)" ::: "memory")

__device__ __forceinline__ void ldsload16(const char* g, char* l) {
  __builtin_amdgcn_global_load_lds(
      (const __attribute__((address_space(1))) unsigned int*)g,
      (__attribute__((address_space(3))) unsigned int*)l, 16, 0, 0);
}
// 8-wave (512-thread) linear stage of pre-swizzled image
__device__ __forceinline__ void stageW8(const char* g, char* lds, int bytes,
                                        int wave, int lane) {
  for (int c = wave * 1024; c < bytes; c += 8192)
    ldsload16(g + c + lane * 16, lds + c);
}

// ---------- dispatch 2: fused bucket (blocks 80..207) + weight prep (blocks 0..79) ----------
__global__ __launch_bounds__(256) void k_fused(
    const int* __restrict__ sid, unsigned short* __restrict__ perm,
    int* __restrict__ cnt,
    const float* __restrict__ Wa1, const float* __restrict__ Wa2,
    const float* __restrict__ Wa3, const float* __restrict__ Wc1,
    const float* __restrict__ Wc2, char* __restrict__ G) {
  __shared__ __align__(16) char smem[32768];
  const int tid = threadIdx.x;
  const int bid = blockIdx.x;

  if (bid >= 80) {
    int* lc = (int*)smem;
    int* lb = lc + St;
    const int b = (bid - 80) * 256 + tid;
    if (tid < St) lc[tid] = 0;
    __syncthreads();
    const int s = sid[b];
    const int p = atomicAdd(&lc[s], 1);
    __syncthreads();
    if (tid < St) lb[tid] = atomicAdd(&cnt[tid * 16], lc[tid]);  // padded: 1 line/skill
    __syncthreads();
    perm[s * Bt + lb[s] + p] = (unsigned short)b;
    return;
  }

  const int s = bid / 5, mm = bid % 5;
  char* Gs = G + s * SKB;

  if (mm == 2) {  // Wa3: 128x17 -> direct swizzled scatter
    const float* src = Wa3 + s * Ht * At;
    for (int e = tid; e < Ht * At; e += 256) {
      const int k = e / At, n = e - k * At;
      *(unsigned short*)(Gs + OA3 + n * 256 + ((2 * k) ^ ((n & 7) << 4))) =
          f2bf(src[e]);
    }
    return;
  }

  const float* src; int K, off;
  if (mm == 0)      { src = Wa1 + s * Dt * Ht; K = 64;  off = OA1; }
  else if (mm == 1) { src = Wa2 + s * Ht * Ht; K = 128; off = OA2; }
  else if (mm == 3) { src = Wc1 + s * Dt * Ht; K = 64;  off = OC1; }
  else              { src = Wc2 + s * Ht * Ht; K = 128; off = OC2; }
  const int SB = 2 * K;
  const int lsb = (K == 128) ? 8 : 7;
  const int pm = (K == 128) ? 15 : 7;

  unsigned short* lds = (unsigned short*)smem;
  for (int it = 0; it < K / 8; ++it) {
    const int f = (it * 256 + tid) * 4;
    const int k = f >> 7, n0 = f & 127;
    const f32x4 v = *(const f32x4*)(src + f);
#pragma unroll
    for (int j = 0; j < 4; ++j) {
      const int n = n0 + j;
      const int byte = n * SB + ((2 * k) ^ (((n >> 2) & pm) << 4));
      lds[byte >> 1] = f2bf(v[j]);
    }
  }
  __syncthreads();
  const int nbytes = 128 * SB;
  for (int it = 0; it < nbytes / 2048; ++it) {
    const int q = (it * 256 + tid) * 8;
    const int n = q >> lsb, r = q & (SB - 1);
    const int srcoff = (r ^ ((n & 7) << 4)) ^ (((n >> 2) & pm) << 4);
    const unsigned long long v8 =
        *(const unsigned long long*)(smem + n * SB + srcoff);
    *(unsigned long long*)(Gs + off + q) = v8;
  }
}

__device__ __forceinline__ bf16x8 wrd(const char* base, int srw, int n, int c,
                                      int lg, int msw) {
  return *(const bf16x8*)(base + n * srw + ((c + lg * 16) ^ msw));
}

// store tanh(acc+bias) for BOTH rowsets (shared b2)
__device__ __forceinline__ void storeh2(char* hw0, char* hw1, int msw, int lg,
                                        int t, const f32x4 a0, const f32x4 a1,
                                        const f32x4 b2) {
  const unsigned lo0 = cvtpk(tanh_fb(a0[0], b2[0]), tanh_fb(a0[1], b2[1]));
  const unsigned hi0 = cvtpk(tanh_fb(a0[2], b2[2]), tanh_fb(a0[3], b2[3]));
  const unsigned lo1 = cvtpk(tanh_fb(a1[0], b2[0]), tanh_fb(a1[1], b2[1]));
  const unsigned hi1 = cvtpk(tanh_fb(a1[2], b2[2]), tanh_fb(a1[3], b2[3]));
  const int off = (32 * t + 8 * lg) ^ msw;
  *(unsigned long long*)(hw0 + off) =
      (unsigned long long)lo0 | ((unsigned long long)hi0 << 32);
  *(unsigned long long*)(hw1 + off) =
      (unsigned long long)lo1 | ((unsigned long long)hi1 << 32);
}

// ---------- dispatch 3: 1 block/CU, 8 waves x 32 rows (2 rowsets), staged once ----------
__global__ __launch_bounds__(512, 1) void k_main(
    const float* __restrict__ obs,
    const float* __restrict__ ba1, const float* __restrict__ ba2,
    const float* __restrict__ ba3, const float* __restrict__ bc1,
    const float* __restrict__ bc2, const float* __restrict__ Wc3,
    const float* __restrict__ bc3,
    const int* __restrict__ cnt, const unsigned short* __restrict__ perm,
    const char* __restrict__ G, float* __restrict__ out) {
  __shared__ __align__(16) char wbuf[57344];  // L1@0 16K | L2@16K 32K | L3@48K 8K
  __shared__ __align__(16) char hbuf[65536];  // 256 rows x 256B, wave-private rows

  const int tid = threadIdx.x;
  const int w = tid >> 6, lane = tid & 63;
  const int m = lane & 15, lg = lane >> 4;
  const bool actor = (blockIdx.x == 0);
  const int s = blockIdx.y, idx = blockIdx.z;   // idx in 0..7
  const char* Gs = G + s * SKB;

  // stage all weights ONCE (issued first, zero dependencies)
  if (actor) {
    stageW8(Gs + OA1, wbuf, 16384, w, lane);
    stageW8(Gs + OA2, wbuf + 16384, 32768, w, lane);
    stageW8(Gs + OA3, wbuf + 49152, 8192, w, lane);
  } else {
    stageW8(Gs + OC1, wbuf, 16384, w, lane);
    stageW8(Gs + OC2, wbuf + 16384, 32768, w, lane);
  }

  const int cs = cnt[s * 16];
  const unsigned short* pb = perm + s * Bt;
  const int roff0 = w * 32 + m, roff1 = roff0 + 16;

  // chunk 0 rows + obs (overlaps staging)
  int pos = idx * 256;
  int r0 = min((int)pb[pos + roff0], Bt - 1);   // stale-tail guard
  int r1 = min((int)pb[pos + roff1], Bt - 1);
  f32x4 c0, c1, c2, c3, c4, c5, c6, c7;
  {
    const float* a0p = obs + r0 * Dt + lg * 8;
    const float* a1p = obs + r1 * Dt + lg * 8;
    c0 = *(const f32x4*)(a0p);      c1 = *(const f32x4*)(a0p + 4);
    c2 = *(const f32x4*)(a0p + 32); c3 = *(const f32x4*)(a0p + 36);
    c4 = *(const f32x4*)(a1p);      c5 = *(const f32x4*)(a1p + 4);
    c6 = *(const f32x4*)(a1p + 32); c7 = *(const f32x4*)(a1p + 36);
  }

  char* hw0 = hbuf + (w * 32 + m) * 256;
  char* hw1 = hw0 + 4096;                 // +16 rows
  const int msw = (m & 7) << 4;

  const float* B1 = (actor ? ba1 : bc1) + s * Ht;
  const float* B2 = (actor ? ba2 : bc2) + s * Ht;
  const float* ba3s = ba3 + s * At;
  const float* wc3s = Wc3 + s * Ht;
  const float bc3s = bc3[s];

  __syncthreads();                        // the ONLY barrier

  while (pos < cs) {
    // pack XB for both rowsets
    union { bf16x8 v; unsigned u[4]; } X0, X1, Y0, Y1;
    X0.u[0] = cvtpk(c0[0], c0[1]); X0.u[1] = cvtpk(c0[2], c0[3]);
    X0.u[2] = cvtpk(c1[0], c1[1]); X0.u[3] = cvtpk(c1[2], c1[3]);
    X1.u[0] = cvtpk(c2[0], c2[1]); X1.u[1] = cvtpk(c2[2], c2[3]);
    X1.u[2] = cvtpk(c3[0], c3[1]); X1.u[3] = cvtpk(c3[2], c3[3]);
    Y0.u[0] = cvtpk(c4[0], c4[1]); Y0.u[1] = cvtpk(c4[2], c4[3]);
    Y0.u[2] = cvtpk(c5[0], c5[1]); Y0.u[3] = cvtpk(c5[2], c5[3]);
    Y1.u[0] = cvtpk(c6[0], c6[1]); Y1.u[1] = cvtpk(c6[2], c6[3]);
    Y1.u[2] = cvtpk(c7[0], c7[1]); Y1.u[3] = cvtpk(c7[2], c7[3]);
    const bool v0 = (pos + roff0) < cs, v1 = (pos + roff1) < cs;
    const int or0 = r0, or1 = r1;

    // prefetch next chunk (rare; hidden under compute)
    const int npos = pos + 2048;
    if (npos < cs) {
      r0 = min((int)pb[npos + roff0], Bt - 1);
      r1 = min((int)pb[npos + roff1], Bt - 1);
      const float* a0p = obs + r0 * Dt + lg * 8;
      const float* a1p = obs + r1 * Dt + lg * 8;
      c0 = *(const f32x4*)(a0p);      c1 = *(const f32x4*)(a0p + 4);
      c2 = *(const f32x4*)(a0p + 32); c3 = *(const f32x4*)(a0p + 36);
      c4 = *(const f32x4*)(a1p);      c5 = *(const f32x4*)(a1p + 4);
      c6 = *(const f32x4*)(a1p + 32); c7 = *(const f32x4*)(a1p + 36);
    }

    // ---- layer 1 (K=64): each weight frag -> 2 MFMAs ----
#pragma unroll
    for (int nt = 0; nt < 8; ++nt) {
      const bf16x8 a0 = wrd(wbuf, 128, nt * 16 + m, 0, lg, msw);
      const bf16x8 a1 = wrd(wbuf, 128, nt * 16 + m, 64, lg, msw);
      f32x4 acc0 = {0.f, 0.f, 0.f, 0.f}, acc1 = {0.f, 0.f, 0.f, 0.f};
      acc0 = MFMA(a0, X0.v, acc0); acc0 = MFMA(a1, X1.v, acc0);
      acc1 = MFMA(a0, Y0.v, acc1); acc1 = MFMA(a1, Y1.v, acc1);
      const f32x4 bb = *(const f32x4*)(B1 + nt * 16 + lg * 4);
      storeh2(hw0, hw1, msw, lg, nt, acc0, acc1, bb + bb);
    }
    LGKM0();
    const bf16x8 h0 = *(const bf16x8*)(hw0 + ((0   + 16 * lg) ^ msw));
    const bf16x8 h1 = *(const bf16x8*)(hw0 + ((64  + 16 * lg) ^ msw));
    const bf16x8 h2 = *(const bf16x8*)(hw0 + ((128 + 16 * lg) ^ msw));
    const bf16x8 h3 = *(const bf16x8*)(hw0 + ((192 + 16 * lg) ^ msw));
    const bf16x8 g0 = *(const bf16x8*)(hw1 + ((0   + 16 * lg) ^ msw));
    const bf16x8 g1 = *(const bf16x8*)(hw1 + ((64  + 16 * lg) ^ msw));
    const bf16x8 g2 = *(const bf16x8*)(hw1 + ((128 + 16 * lg) ^ msw));
    const bf16x8 g3 = *(const bf16x8*)(hw1 + ((192 + 16 * lg) ^ msw));
    LGKM0();   // reads done before layer-2 overwrites (WAR)

    if (actor) {
      // ---- actor layer 2 (K=128) ----
#pragma unroll
      for (int nt = 0; nt < 8; ++nt) {
        const int n = nt * 16 + m;
        const bf16x8 w0 = wrd(wbuf + 16384, 256, n, 0, lg, msw);
        const bf16x8 w1 = wrd(wbuf + 16384, 256, n, 64, lg, msw);
        const bf16x8 w2 = wrd(wbuf + 16384, 256, n, 128, lg, msw);
        const bf16x8 w3 = wrd(wbuf + 16384, 256, n, 192, lg, msw);
        f32x4 acc0 = {0.f, 0.f, 0.f, 0.f}, acc1 = {0.f, 0.f, 0.f, 0.f};
        acc0 = MFMA(w0, h0, acc0); acc0 = MFMA(w1, h1, acc0);
        acc0 = MFMA(w2, h2, acc0); acc0 = MFMA(w3, h3, acc0);
        acc1 = MFMA(w0, g0, acc1); acc1 = MFMA(w1, g1, acc1);
        acc1 = MFMA(w2, g2, acc1); acc1 = MFMA(w3, g3, acc1);
        const f32x4 bb = *(const f32x4*)(B2 + nt * 16 + lg * 4);
        storeh2(hw0, hw1, msw, lg, nt, acc0, acc1, bb + bb);
      }
      LGKM0();
      const bf16x8 H0 = *(const bf16x8*)(hw0 + ((0   + 16 * lg) ^ msw));
      const bf16x8 H1 = *(const bf16x8*)(hw0 + ((64  + 16 * lg) ^ msw));
      const bf16x8 H2 = *(const bf16x8*)(hw0 + ((128 + 16 * lg) ^ msw));
      const bf16x8 H3 = *(const bf16x8*)(hw0 + ((192 + 16 * lg) ^ msw));
      const bf16x8 G0 = *(const bf16x8*)(hw1 + ((0   + 16 * lg) ^ msw));
      const bf16x8 G1 = *(const bf16x8*)(hw1 + ((64  + 16 * lg) ^ msw));
      const bf16x8 G2 = *(const bf16x8*)(hw1 + ((128 + 16 * lg) ^ msw));
      const bf16x8 G3 = *(const bf16x8*)(hw1 + ((192 + 16 * lg) ^ msw));
      // ---- actor layer 3 ----
      const char* W3 = wbuf + 49152;
      const bf16x8 e0 = wrd(W3, 256, m, 0, lg, msw);
      const bf16x8 e1 = wrd(W3, 256, m, 64, lg, msw);
      const bf16x8 e2 = wrd(W3, 256, m, 128, lg, msw);
      const bf16x8 e3 = wrd(W3, 256, m, 192, lg, msw);
      const bf16x8 f0 = wrd(W3, 256, 16 + m, 0, lg, msw);
      const bf16x8 f1 = wrd(W3, 256, 16 + m, 64, lg, msw);
      const bf16x8 f2 = wrd(W3, 256, 16 + m, 128, lg, msw);
      const bf16x8 f3 = wrd(W3, 256, 16 + m, 192, lg, msw);
      f32x4 p0 = {0.f, 0.f, 0.f, 0.f}, p1 = {0.f, 0.f, 0.f, 0.f};
      f32x4 q0 = {0.f, 0.f, 0.f, 0.f}, q1 = {0.f, 0.f, 0.f, 0.f};
      p0 = MFMA(e0, H0, p0); p0 = MFMA(e1, H1, p0);
      p0 = MFMA(e2, H2, p0); p0 = MFMA(e3, H3, p0);
      p1 = MFMA(f0, H0, p1); p1 = MFMA(f1, H1, p1);
      p1 = MFMA(f2, H2, p1); p1 = MFMA(f3, H3, p1);
      q0 = MFMA(e0, G0, q0); q0 = MFMA(e1, G1, q0);
      q0 = MFMA(e2, G2, q0); q0 = MFMA(e3, G3, q0);
      q1 = MFMA(f0, G0, q1); q1 = MFMA(f1, G1, q1);
      q1 = MFMA(f2, G2, q1); q1 = MFMA(f3, G3, q1);
      if (v0) {
        float* orow = out + or0 * At;
#pragma unroll
        for (int i = 0; i < 4; ++i)
          orow[4 * lg + i] = p0[i] + ba3s[4 * lg + i];
        if (lg == 0) orow[16] = p1[0] + ba3s[16];
      }
      if (v1) {
        float* orow = out + or1 * At;
#pragma unroll
        for (int i = 0; i < 4; ++i)
          orow[4 * lg + i] = q0[i] + ba3s[4 * lg + i];
        if (lg == 0) orow[16] = q1[0] + ba3s[16];
      }
    } else {
      // ---- critic layer 2 + value ----
      float vp0 = 0.f, vp1 = 0.f;
#pragma unroll
      for (int nt = 0; nt < 8; ++nt) {
        const int n = nt * 16 + m;
        const bf16x8 w0 = wrd(wbuf + 16384, 256, n, 0, lg, msw);
        const bf16x8 w1 = wrd(wbuf + 16384, 256, n, 64, lg, msw);
        const bf16x8 w2 = wrd(wbuf + 16384, 256, n, 128, lg, msw);
        const bf16x8 w3 = wrd(wbuf + 16384, 256, n, 192, lg, msw);
        f32x4 acc0 = {0.f, 0.f, 0.f, 0.f}, acc1 = {0.f, 0.f, 0.f, 0.f};
        acc0 = MFMA(w0, h0, acc0); acc0 = MFMA(w1, h1, acc0);
        acc0 = MFMA(w2, h2, acc0); acc0 = MFMA(w3, h3, acc0);
        acc1 = MFMA(w0, g0, acc1); acc1 = MFMA(w1, g1, acc1);
        acc1 = MFMA(w2, g2, acc1); acc1 = MFMA(w3, g3, acc1);
        const f32x4 bb = *(const f32x4*)(B2 + nt * 16 + lg * 4);
        const f32x4 b2 = bb + bb;
        const f32x4 wv = *(const f32x4*)(wc3s + nt * 16 + lg * 4);
#pragma unroll
        for (int i = 0; i < 4; ++i) {
          vp0 = __builtin_fmaf(tanh_fb(acc0[i], b2[i]), wv[i], vp0);
          vp1 = __builtin_fmaf(tanh_fb(acc1[i], b2[i]), wv[i], vp1);
        }
      }
      vp0 += __shfl_xor(vp0, 16); vp0 += __shfl_xor(vp0, 32);
      vp1 += __shfl_xor(vp1, 16); vp1 += __shfl_xor(vp1, 32);
      if (lane < 16) {
        if (v0) out[Bt * At + or0] = vp0 + bc3s;
        if (v1) out[Bt * At + or1] = vp1 + bc3s;
      }
    }
    pos = npos;
  }
}

extern "C" void kernel_launch(void* const* d_in, const int* in_sizes, int n_in,
                              void* d_out, int out_size, void* d_ws, size_t ws_size,
                              hipStream_t stream) {
  const float* obs = (const float*)d_in[0];
  const int* sid   = (const int*)d_in[1];
  const float* Wa1 = (const float*)d_in[2];
  const float* ba1 = (const float*)d_in[3];
  const float* Wa2 = (const float*)d_in[4];
  const float* ba2 = (const float*)d_in[5];
  const float* Wa3 = (const float*)d_in[6];
  const float* ba3 = (const float*)d_in[7];
  const float* Wc1 = (const float*)d_in[8];
  const float* bc1 = (const float*)d_in[9];
  const float* Wc2 = (const float*)d_in[10];
  const float* bc2 = (const float*)d_in[11];
  const float* Wc3 = (const float*)d_in[12];
  const float* bc3 = (const float*)d_in[13];
  float* out = (float*)d_out;
  char* ws = (char*)d_ws;

  int* cnt = (int*)(ws + CNT_OFF);
  unsigned short* perm = (unsigned short*)(ws + PERM_OFF);
  char* G = ws + WB_OFF;

  hipMemsetAsync(cnt, 0, 16 * St * sizeof(int), stream);
  k_fused<<<dim3(208), dim3(256), 0, stream>>>(sid, perm, cnt, Wa1, Wa2, Wa3, Wc1, Wc2, G);
  k_main<<<dim3(2, 16, 8), dim3(512), 0, stream>>>(
      obs, ba1, ba2, ba3, bc1, bc2, Wc3, bc3, cnt, perm, G, out);
}

// Round 11
// 34.070 us; speedup vs baseline: 1.0158x; 1.0158x over previous
//
#include <hip/hip_runtime.h>

#define Bt 32768
#define Dt 64
#define St 16
#define Ht 128
#define At 17

typedef __attribute__((ext_vector_type(8))) short bf16x8;
typedef __attribute__((ext_vector_type(4))) float f32x4;

// ---- workspace layout (bytes) ----
#define CNT_OFF   0          // int[16]
#define PERM_OFF  128        // u16 [S][B]  (1 MiB)
#define WB_OFF    1049600    // bf16 transposed weight images [n][k], XOR-swizzled
#define OA1 0        // Wa1^T: 128 rows x 128B (K=64)
#define OA2 16384    // Wa2^T: 128 rows x 256B (K=128)
#define OA3 49152    // Wa3^T: 32-row region, rows >=17 unused garbage
#define OC1 57344    // Wc1^T
#define OC2 73728    // Wc2^T
#define SKB 106496   // per-skill stride

__device__ __forceinline__ unsigned short f2bf(float f) {
  union { float f; unsigned u; } v; v.f = f;
  unsigned r = v.u + 0x7FFFu + ((v.u >> 16) & 1u);  // RNE
  return (unsigned short)(r >> 16);
}

__device__ __forceinline__ unsigned cvtpk(float a, float b) {
  unsigned r;
  asm("v_cvt_pk_bf16_f32 %0, %1, %2" : "=v"(r) : "v"(a), "v"(b));
  return r;
}

// tanh(acc + bias) with b2 = 2*bias precomputed
__device__ __forceinline__ float tanh_fb(float acc, float b2) {
  const float t = __expf(__builtin_fmaf(acc, 2.0f, b2));  // inf-safe
  const float r = __builtin_amdgcn_rcpf(t + 1.0f);
  return __builtin_fmaf(-2.0f, r, 1.0f);
}

__device__ __forceinline__ f32x4 MFMA(bf16x8 a, bf16x8 b, f32x4 c) {
  return __builtin_amdgcn_mfma_f32_16x16x32_bf16(a, b, c, 0, 0, 0);
}

#define LGKM0() asm volatile("s_waitcnt lgkmcnt(0)" ::: "memory")

__device__ __forceinline__ void ldsload16(const char* g, char* l) {
  __builtin_amdgcn_global_load_lds(
      (const __attribute__((address_space(1))) unsigned int*)g,
      (__attribute__((address_space(3))) unsigned int*)l, 16, 0, 0);
}
__device__ __forceinline__ void stageW(const char* g, char* lds, int bytes,
                                       int wave, int lane) {
  for (int c = wave * 1024; c < bytes; c += 4096)
    ldsload16(g + c + lane * 16, lds + c);
}

// ---------- dispatch 2: prep (blocks 0..111: s=bid/7,t=bid%7) + bucket (112..127) ----------
__global__ __launch_bounds__(256) void k_fused(
    const int* __restrict__ sid, unsigned short* __restrict__ perm,
    int* __restrict__ cnt,
    const float* __restrict__ Wa1, const float* __restrict__ Wa2,
    const float* __restrict__ Wa3, const float* __restrict__ Wc1,
    const float* __restrict__ Wc2, char* __restrict__ G) {
  __shared__ __align__(16) char smem[32768];
  const int tid = threadIdx.x;
  const int bid = blockIdx.x;

  if (bid >= 112) {
    // ---- bucket: ballot-histogram + rank scatter; 16 atomics/block ----
    __shared__ int wh[4][16], wbs[4][16];
    const int b = bid - 112;
    const int w = tid >> 6, lane = tid & 63;
    const int ebase = b * 2048 + w * 512;
    int c[16];
#pragma unroll
    for (int sk = 0; sk < 16; ++sk) c[sk] = 0;
#pragma unroll
    for (int r = 0; r < 8; ++r) {
      const int v = sid[ebase + r * 64 + lane];
#pragma unroll
      for (int sk = 0; sk < 16; ++sk)
        c[sk] += (int)__popcll(__ballot(v == sk));
    }
    if (lane == 0) {
#pragma unroll
      for (int sk = 0; sk < 16; ++sk) wh[w][sk] = c[sk];
    }
    __syncthreads();
    if (tid < 16) {
      const int sk = tid;
      const int t0 = wh[0][sk], t1 = wh[1][sk], t2 = wh[2][sk], t3 = wh[3][sk];
      const int g = atomicAdd(&cnt[sk], t0 + t1 + t2 + t3);
      wbs[0][sk] = g;
      wbs[1][sk] = g + t0;
      wbs[2][sk] = g + t0 + t1;
      wbs[3][sk] = g + t0 + t1 + t2;
    }
    __syncthreads();
    int wb[16];
#pragma unroll
    for (int sk = 0; sk < 16; ++sk) wb[sk] = wbs[w][sk];
    const unsigned long long lt = (1ULL << lane) - 1ULL;
#pragma unroll
    for (int r = 0; r < 8; ++r) {
      const int e = ebase + r * 64 + lane;
      const int v = sid[e];
#pragma unroll
      for (int sk = 0; sk < 16; ++sk) {
        const unsigned long long mk = __ballot(v == sk);
        if (v == sk) perm[sk * Bt + wb[sk] + (int)__popcll(mk & lt)] =
            (unsigned short)e;
        wb[sk] += (int)__popcll(mk);
      }
    }
    return;
  }

  const int s = bid / 7, t = bid % 7;
  char* Gs = G + s * SKB;

  if (t == 3) {  // Wa3: 128x17 -> direct swizzled scatter
    const float* src = Wa3 + s * Ht * At;
    for (int e = tid; e < Ht * At; e += 256) {
      const int k = e / At, n = e - k * At;
      *(unsigned short*)(Gs + OA3 + n * 256 + ((2 * k) ^ ((n & 7) << 4))) =
          f2bf(src[e]);
    }
    return;
  }

  unsigned short* lds = (unsigned short*)smem;
  if (t == 0 || t == 4) {
    // ---- K=64 full matrix (Wa1 / Wc1): 128 rows x 128B ----
    const float* src = (t == 0 ? Wa1 : Wc1) + s * Dt * Ht;
    const int off = (t == 0) ? OA1 : OC1;
    for (int it = 0; it < 8; ++it) {
      const int f = (it * 256 + tid) * 4;
      const int k = f >> 7, n0 = f & 127;
      const f32x4 v = *(const f32x4*)(src + f);
#pragma unroll
      for (int j = 0; j < 4; ++j) {
        const int n = n0 + j;
        const int byte = n * 128 + ((2 * k) ^ (((n >> 2) & 7) << 4));
        lds[byte >> 1] = f2bf(v[j]);
      }
    }
    __syncthreads();
    for (int it = 0; it < 8; ++it) {
      const int q = (it * 256 + tid) * 8;
      const int n = q >> 7, r = q & 127;
      const int srcoff = (r ^ ((n & 7) << 4)) ^ (((n >> 2) & 7) << 4);
      *(unsigned long long*)(Gs + off + q) =
          *(const unsigned long long*)(smem + n * 128 + srcoff);
    }
  } else {
    // ---- K=128 half matrix (Wa2 / Wc2, 64 n-rows per block) ----
    const bool isA = (t <= 2);
    const float* src = (isA ? Wa2 : Wc2) + s * Ht * Ht;
    const int off = isA ? OA2 : OC2;
    const int nhalf = ((t == 2) || (t == 6)) ? 64 : 0;
    for (int it = 0; it < 8; ++it) {
      const int e4 = it * 256 + tid;           // 2048 f32x4 groups
      const int k = e4 >> 4, nl0 = (e4 & 15) * 4;
      const f32x4 v = *(const f32x4*)(src + k * 128 + nhalf + nl0);
#pragma unroll
      for (int j = 0; j < 4; ++j) {
        const int nl = nl0 + j;
        const int byte = nl * 256 + ((2 * k) ^ (((nl >> 2) & 15) << 4));
        lds[byte >> 1] = f2bf(v[j]);
      }
    }
    __syncthreads();
    for (int it = 0; it < 8; ++it) {
      const int q = (it * 256 + tid) * 8;      // 16KB half image
      const int nl = q >> 8, r = q & 255;
      const int srcoff = (r ^ ((nl & 7) << 4)) ^ (((nl >> 2) & 15) << 4);
      *(unsigned long long*)(Gs + off + (nhalf + nl) * 256 + r) =
          *(const unsigned long long*)(smem + nl * 256 + srcoff);
    }
  }
}

__device__ __forceinline__ bf16x8 wrd(const char* base, int srw, int n, int c,
                                      int lg, int msw) {
  return *(const bf16x8*)(base + n * srw + (((c) + lg * 16) ^ msw));
}

__device__ __forceinline__ void storeh(char* hw, int msw, int lg, int t,
                                       const f32x4 acc, const float* BB) {
  const f32x4 bb = *(const f32x4*)(BB + t * 16 + lg * 4);
  const f32x4 b2 = bb + bb;
  const unsigned lo = cvtpk(tanh_fb(acc[0], b2[0]), tanh_fb(acc[1], b2[1]));
  const unsigned hi = cvtpk(tanh_fb(acc[2], b2[2]), tanh_fb(acc[3], b2[3]));
  *(unsigned long long*)(hw + ((32 * t + 8 * lg) ^ msw)) =
      (unsigned long long)lo | ((unsigned long long)hi << 32);
}

// ---- one 64-row tile, actor role ----
__device__ __forceinline__ void tile_actor(
    int tbase, int rnext, bool dopref, int& rowcur,
    f32x4& cx0, f32x4& cx1, f32x4& cx2, f32x4& cx3,
    const char* wbuf, char* hw, const float* obs,
    const float* ba1s, const float* ba2s, const float* ba3s, float* out,
    int m, int lg, int msw, int wm, int cs) {
  union { bf16x8 v; unsigned u[4]; } XB0, XB1;
  XB0.u[0] = cvtpk(cx0[0], cx0[1]); XB0.u[1] = cvtpk(cx0[2], cx0[3]);
  XB0.u[2] = cvtpk(cx1[0], cx1[1]); XB0.u[3] = cvtpk(cx1[2], cx1[3]);
  XB1.u[0] = cvtpk(cx2[0], cx2[1]); XB1.u[1] = cvtpk(cx2[2], cx2[3]);
  XB1.u[2] = cvtpk(cx3[0], cx3[1]); XB1.u[3] = cvtpk(cx3[2], cx3[3]);
  const int myrow = rowcur;
  if (dopref) {  // next tile's obs: in flight across this tile's compute
    const float* ap = obs + rnext * Dt + lg * 8;
    cx0 = *(const f32x4*)(ap);      cx1 = *(const f32x4*)(ap + 4);
    cx2 = *(const f32x4*)(ap + 32); cx3 = *(const f32x4*)(ap + 36);
  }
  rowcur = rnext;
#pragma unroll
  for (int nt = 0; nt < 8; ++nt) {
    const bf16x8 a0 = wrd(wbuf, 128, nt * 16 + m, 0, lg, msw);
    const bf16x8 a1 = wrd(wbuf, 128, nt * 16 + m, 64, lg, msw);
    f32x4 acc = {0.f, 0.f, 0.f, 0.f};
    acc = MFMA(a0, XB0.v, acc);
    acc = MFMA(a1, XB1.v, acc);
    storeh(hw, msw, lg, nt, acc, ba1s);
  }
  LGKM0();
  const bf16x8 h0 = *(const bf16x8*)(hw + ((0   + 16 * lg) ^ msw));
  const bf16x8 h1 = *(const bf16x8*)(hw + ((64  + 16 * lg) ^ msw));
  const bf16x8 h2 = *(const bf16x8*)(hw + ((128 + 16 * lg) ^ msw));
  const bf16x8 h3 = *(const bf16x8*)(hw + ((192 + 16 * lg) ^ msw));
#pragma unroll
  for (int nt = 0; nt < 8; ++nt) {
    const int n = nt * 16 + m;
    const bf16x8 w0 = wrd(wbuf + 16384, 256, n, 0, lg, msw);
    const bf16x8 w1 = wrd(wbuf + 16384, 256, n, 64, lg, msw);
    const bf16x8 w2 = wrd(wbuf + 16384, 256, n, 128, lg, msw);
    const bf16x8 w3 = wrd(wbuf + 16384, 256, n, 192, lg, msw);
    f32x4 acc = {0.f, 0.f, 0.f, 0.f};
    acc = MFMA(w0, h0, acc); acc = MFMA(w1, h1, acc);
    acc = MFMA(w2, h2, acc); acc = MFMA(w3, h3, acc);
    storeh(hw, msw, lg, nt, acc, ba2s);
  }
  LGKM0();
  const bf16x8 H0 = *(const bf16x8*)(hw + ((0   + 16 * lg) ^ msw));
  const bf16x8 H1 = *(const bf16x8*)(hw + ((64  + 16 * lg) ^ msw));
  const bf16x8 H2 = *(const bf16x8*)(hw + ((128 + 16 * lg) ^ msw));
  const bf16x8 H3 = *(const bf16x8*)(hw + ((192 + 16 * lg) ^ msw));
  const char* W3 = wbuf + 49152;
  const bf16x8 e0 = wrd(W3, 256, m, 0, lg, msw);
  const bf16x8 e1 = wrd(W3, 256, m, 64, lg, msw);
  const bf16x8 e2 = wrd(W3, 256, m, 128, lg, msw);
  const bf16x8 e3 = wrd(W3, 256, m, 192, lg, msw);
  const bf16x8 f0 = wrd(W3, 256, 16 + m, 0, lg, msw);
  const bf16x8 f1 = wrd(W3, 256, 16 + m, 64, lg, msw);
  const bf16x8 f2 = wrd(W3, 256, 16 + m, 128, lg, msw);
  const bf16x8 f3 = wrd(W3, 256, 16 + m, 192, lg, msw);
  f32x4 p0 = {0.f, 0.f, 0.f, 0.f}, p1 = {0.f, 0.f, 0.f, 0.f};
  p0 = MFMA(e0, H0, p0); p0 = MFMA(e1, H1, p0);
  p0 = MFMA(e2, H2, p0); p0 = MFMA(e3, H3, p0);
  p1 = MFMA(f0, H0, p1); p1 = MFMA(f1, H1, p1);
  p1 = MFMA(f2, H2, p1); p1 = MFMA(f3, H3, p1);
  if (tbase + wm < cs) {
    float* orow = out + myrow * At;
#pragma unroll
    for (int i = 0; i < 4; ++i)                 // n = 4lg+i in 0..15
      orow[4 * lg + i] = p0[i] + ba3s[4 * lg + i];
    if (lg == 0) orow[16] = p1[0] + ba3s[16];   // n = 16
  }
}

// ---- one 64-row tile, critic role ----
__device__ __forceinline__ void tile_critic(
    int tbase, int rnext, bool dopref, int& rowcur,
    f32x4& cx0, f32x4& cx1, f32x4& cx2, f32x4& cx3,
    const char* wbuf, char* hw, const float* obs,
    const float* bc1s, const float* bc2s, const float* wc3s, float bc3s,
    float* out, int m, int lg, int msw, int wm, int cs, int lane) {
  union { bf16x8 v; unsigned u[4]; } XB0, XB1;
  XB0.u[0] = cvtpk(cx0[0], cx0[1]); XB0.u[1] = cvtpk(cx0[2], cx0[3]);
  XB0.u[2] = cvtpk(cx1[0], cx1[1]); XB0.u[3] = cvtpk(cx1[2], cx1[3]);
  XB1.u[0] = cvtpk(cx2[0], cx2[1]); XB1.u[1] = cvtpk(cx2[2], cx2[3]);
  XB1.u[2] = cvtpk(cx3[0], cx3[1]); XB1.u[3] = cvtpk(cx3[2], cx3[3]);
  const int myrow = rowcur;
  if (dopref) {
    const float* ap = obs + rnext * Dt + lg * 8;
    cx0 = *(const f32x4*)(ap);      cx1 = *(const f32x4*)(ap + 4);
    cx2 = *(const f32x4*)(ap + 32); cx3 = *(const f32x4*)(ap + 36);
  }
  rowcur = rnext;
#pragma unroll
  for (int nt = 0; nt < 8; ++nt) {
    const bf16x8 a0 = wrd(wbuf, 128, nt * 16 + m, 0, lg, msw);
    const bf16x8 a1 = wrd(wbuf, 128, nt * 16 + m, 64, lg, msw);
    f32x4 acc = {0.f, 0.f, 0.f, 0.f};
    acc = MFMA(a0, XB0.v, acc);
    acc = MFMA(a1, XB1.v, acc);
    storeh(hw, msw, lg, nt, acc, bc1s);
  }
  LGKM0();
  const bf16x8 h0 = *(const bf16x8*)(hw + ((0   + 16 * lg) ^ msw));
  const bf16x8 h1 = *(const bf16x8*)(hw + ((64  + 16 * lg) ^ msw));
  const bf16x8 h2 = *(const bf16x8*)(hw + ((128 + 16 * lg) ^ msw));
  const bf16x8 h3 = *(const bf16x8*)(hw + ((192 + 16 * lg) ^ msw));
  float vp = 0.f;
#pragma unroll
  for (int nt = 0; nt < 8; ++nt) {
    const int n = nt * 16 + m;
    const bf16x8 w0 = wrd(wbuf + 16384, 256, n, 0, lg, msw);
    const bf16x8 w1 = wrd(wbuf + 16384, 256, n, 64, lg, msw);
    const bf16x8 w2 = wrd(wbuf + 16384, 256, n, 128, lg, msw);
    const bf16x8 w3 = wrd(wbuf + 16384, 256, n, 192, lg, msw);
    f32x4 acc = {0.f, 0.f, 0.f, 0.f};
    acc = MFMA(w0, h0, acc); acc = MFMA(w1, h1, acc);
    acc = MFMA(w2, h2, acc); acc = MFMA(w3, h3, acc);
    const f32x4 bb = *(const f32x4*)(bc2s + nt * 16 + lg * 4);
    const f32x4 b2 = bb + bb;
    const f32x4 wv = *(const f32x4*)(wc3s + nt * 16 + lg * 4);
#pragma unroll
    for (int i = 0; i < 4; ++i)
      vp = __builtin_fmaf(tanh_fb(acc[i], b2[i]), wv[i], vp);
  }
  vp += __shfl_xor(vp, 16);
  vp += __shfl_xor(vp, 32);
  if (lane < 16 && (tbase + wm < cs)) out[Bt * At + myrow] = vp + bc3s;
}

// ---------- dispatch 3: persistent per-(skill,role) blocks; staged once (R9) ----------
__global__ __launch_bounds__(256, 2) void k_main(
    const float* __restrict__ obs,
    const float* __restrict__ ba1, const float* __restrict__ ba2,
    const float* __restrict__ ba3, const float* __restrict__ bc1,
    const float* __restrict__ bc2, const float* __restrict__ Wc3,
    const float* __restrict__ bc3,
    const int* __restrict__ cnt, const unsigned short* __restrict__ perm,
    const char* __restrict__ G, float* __restrict__ out) {
  __shared__ __align__(16) char wbuf[57344];  // L1@0 16K | L2@16K 32K | L3@48K 8K
  __shared__ __align__(16) char hbuf[16384];  // 64 rows x 256B, wave-private rows

  const int tid = threadIdx.x;
  const int wave = tid >> 6, lane = tid & 63;
  const int m = lane & 15, lg = lane >> 4;
  const bool actor = (blockIdx.x == 0);
  const int s = blockIdx.y, idx = blockIdx.z;
  const char* Gs = G + s * SKB;
  const int wm = wave * 16 + m;

  // perm for this block's (up to 3) tiles: no cnt dependency -> issue first
  const unsigned short* pb = perm + s * Bt;
  int r0 = pb[idx * 64 + wm];
  int r1 = pb[(idx + 16) * 64 + wm];
  int r2 = pb[(idx + 32) * 64 + wm];
  const int cs = cnt[s];

  // stage all weights ONCE
  if (actor) {
    stageW(Gs + OA1, wbuf, 16384, wave, lane);
    stageW(Gs + OA2, wbuf + 16384, 32768, wave, lane);
    stageW(Gs + OA3, wbuf + 49152, 8192, wave, lane);
  } else {
    stageW(Gs + OC1, wbuf, 16384, wave, lane);
    stageW(Gs + OC2, wbuf + 16384, 32768, wave, lane);
  }

  r0 = min(r0, Bt - 1); r1 = min(r1, Bt - 1); r2 = min(r2, Bt - 1);
  const int nt = (cs + 63) >> 6;

  f32x4 cx0, cx1, cx2, cx3;
  {
    const float* ap = obs + r0 * Dt + lg * 8;
    cx0 = *(const f32x4*)(ap);      cx1 = *(const f32x4*)(ap + 4);
    cx2 = *(const f32x4*)(ap + 32); cx3 = *(const f32x4*)(ap + 36);
  }

  char* hw = hbuf + wm * 256;
  const int msw = (m & 7) << 4;
  __syncthreads();                       // the ONLY barrier

  int rowcur = r0;
  if (actor) {
    const float* ba1s = ba1 + s * Ht;
    const float* ba2s = ba2 + s * Ht;
    const float* ba3s = ba3 + s * At;
    tile_actor(idx * 64, r1, true, rowcur, cx0, cx1, cx2, cx3,
               wbuf, hw, obs, ba1s, ba2s, ba3s, out, m, lg, msw, wm, cs);
    if (idx + 16 < nt)
      tile_actor((idx + 16) * 64, r2, true, rowcur, cx0, cx1, cx2, cx3,
                 wbuf, hw, obs, ba1s, ba2s, ba3s, out, m, lg, msw, wm, cs);
    if (idx + 32 < nt)
      tile_actor((idx + 32) * 64, r2, false, rowcur, cx0, cx1, cx2, cx3,
                 wbuf, hw, obs, ba1s, ba2s, ba3s, out, m, lg, msw, wm, cs);
  } else {
    const float* bc1s = bc1 + s * Ht;
    const float* bc2s = bc2 + s * Ht;
    const float* wc3s = Wc3 + s * Ht;
    const float bc3s = bc3[s];
    tile_critic(idx * 64, r1, true, rowcur, cx0, cx1, cx2, cx3,
                wbuf, hw, obs, bc1s, bc2s, wc3s, bc3s, out, m, lg, msw, wm, cs, lane);
    if (idx + 16 < nt)
      tile_critic((idx + 16) * 64, r2, true, rowcur, cx0, cx1, cx2, cx3,
                  wbuf, hw, obs, bc1s, bc2s, wc3s, bc3s, out, m, lg, msw, wm, cs, lane);
    if (idx + 32 < nt)
      tile_critic((idx + 32) * 64, r2, false, rowcur, cx0, cx1, cx2, cx3,
                  wbuf, hw, obs, bc1s, bc2s, wc3s, bc3s, out, m, lg, msw, wm, cs, lane);
  }
}

extern "C" void kernel_launch(void* const* d_in, const int* in_sizes, int n_in,
                              void* d_out, int out_size, void* d_ws, size_t ws_size,
                              hipStream_t stream) {
  const float* obs = (const float*)d_in[0];
  const int* sid   = (const int*)d_in[1];
  const float* Wa1 = (const float*)d_in[2];
  const float* ba1 = (const float*)d_in[3];
  const float* Wa2 = (const float*)d_in[4];
  const float* ba2 = (const float*)d_in[5];
  const float* Wa3 = (const float*)d_in[6];
  const float* ba3 = (const float*)d_in[7];
  const float* Wc1 = (const float*)d_in[8];
  const float* bc1 = (const float*)d_in[9];
  const float* Wc2 = (const float*)d_in[10];
  const float* bc2 = (const float*)d_in[11];
  const float* Wc3 = (const float*)d_in[12];
  const float* bc3 = (const float*)d_in[13];
  float* out = (float*)d_out;
  char* ws = (char*)d_ws;

  int* cnt = (int*)(ws + CNT_OFF);
  unsigned short* perm = (unsigned short*)(ws + PERM_OFF);
  char* G = ws + WB_OFF;

  hipMemsetAsync(cnt, 0, St * sizeof(int), stream);
  k_fused<<<dim3(128), dim3(256), 0, stream>>>(sid, perm, cnt, Wa1, Wa2, Wa3, Wc1, Wc2, G);
  k_main<<<dim3(2, 16, 16), dim3(256), 0, stream>>>(
      obs, ba1, ba2, ba3, bc1, bc2, Wc3, bc3, cnt, perm, G, out);
}

// Round 12
// 26.087 us; speedup vs baseline: 1.3266x; 1.3060x over previous
//
#include <hip/hip_runtime.h>

#define Bt 32768
#define Dt 64
#define St 16
#define Ht 128
#define At 17

typedef __attribute__((ext_vector_type(8))) short bf16x8;
typedef __attribute__((ext_vector_type(4))) float f32x4;

// ---- workspace layout (bytes) ----
#define CNT_OFF   0          // int[16]
#define PERM_OFF  128        // u16 [S][B]  (1 MiB)
#define WB_OFF    1049600    // bf16 transposed weight images [n][k], XOR-swizzled
#define OA1 0        // Wa1^T: 128 rows x 128B (K=64)
#define OA2 16384    // Wa2^T: 128 rows x 256B (K=128)
#define OA3 49152    // Wa3^T: 32-row region, rows >=17 unused garbage
#define OC1 57344    // Wc1^T
#define OC2 73728    // Wc2^T
#define SKB 106496   // per-skill stride

__device__ __forceinline__ unsigned short f2bf(float f) {
  union { float f; unsigned u; } v; v.f = f;
  unsigned r = v.u + 0x7FFFu + ((v.u >> 16) & 1u);  // RNE
  return (unsigned short)(r >> 16);
}

__device__ __forceinline__ unsigned cvtpk(float a, float b) {
  unsigned r;
  asm("v_cvt_pk_bf16_f32 %0, %1, %2" : "=v"(r) : "v"(a), "v"(b));
  return r;
}

// tanh(acc + bias) with b2 = 2*bias precomputed
__device__ __forceinline__ float tanh_fb(float acc, float b2) {
  const float t = __expf(__builtin_fmaf(acc, 2.0f, b2));  // inf-safe
  const float r = __builtin_amdgcn_rcpf(t + 1.0f);
  return __builtin_fmaf(-2.0f, r, 1.0f);
}

__device__ __forceinline__ f32x4 MFMA(bf16x8 a, bf16x8 b, f32x4 c) {
  return __builtin_amdgcn_mfma_f32_16x16x32_bf16(a, b, c, 0, 0, 0);
}

#define LGKM0() asm volatile("s_waitcnt lgkmcnt(0)" ::: "memory")

__device__ __forceinline__ void ldsload16(const char* g, char* l) {
  __builtin_amdgcn_global_load_lds(
      (const __attribute__((address_space(1))) unsigned int*)g,
      (__attribute__((address_space(3))) unsigned int*)l, 16, 0, 0);
}
__device__ __forceinline__ void stageW(const char* g, char* lds, int bytes,
                                       int wave, int lane) {
  for (int c = wave * 1024; c < bytes; c += 4096)
    ldsload16(g + c + lane * 16, lds + c);
}

// ---------- dispatch 2: prep (blocks 0..111, split K=128) + bucket (112..239, R9) ----------
__global__ __launch_bounds__(256) void k_fused(
    const int* __restrict__ sid, unsigned short* __restrict__ perm,
    int* __restrict__ cnt,
    const float* __restrict__ Wa1, const float* __restrict__ Wa2,
    const float* __restrict__ Wa3, const float* __restrict__ Wc1,
    const float* __restrict__ Wc2, char* __restrict__ G) {
  __shared__ __align__(16) char smem[32768];
  const int tid = threadIdx.x;
  const int bid = blockIdx.x;

  if (bid >= 112) {
    // ---- bucket: R9-proven per-thread LDS atomics, 128 blocks ----
    int* lc = (int*)smem;
    int* lb = lc + St;
    const int b = (bid - 112) * 256 + tid;
    if (tid < St) lc[tid] = 0;
    __syncthreads();
    const int s = sid[b];
    const int p = atomicAdd(&lc[s], 1);
    __syncthreads();
    if (tid < St) lb[tid] = atomicAdd(&cnt[tid], lc[tid]);
    __syncthreads();
    perm[s * Bt + lb[s] + p] = (unsigned short)b;
    return;
  }

  const int s = bid / 7, t = bid % 7;
  char* Gs = G + s * SKB;

  if (t == 3) {  // Wa3: 128x17 -> direct swizzled scatter
    const float* src = Wa3 + s * Ht * At;
    for (int e = tid; e < Ht * At; e += 256) {
      const int k = e / At, n = e - k * At;
      *(unsigned short*)(Gs + OA3 + n * 256 + ((2 * k) ^ ((n & 7) << 4))) =
          f2bf(src[e]);
    }
    return;
  }

  unsigned short* lds = (unsigned short*)smem;
  if (t == 0 || t == 4) {
    // ---- K=64 full matrix (Wa1 / Wc1): 128 rows x 128B ----
    const float* src = (t == 0 ? Wa1 : Wc1) + s * Dt * Ht;
    const int off = (t == 0) ? OA1 : OC1;
    for (int it = 0; it < 8; ++it) {
      const int f = (it * 256 + tid) * 4;
      const int k = f >> 7, n0 = f & 127;
      const f32x4 v = *(const f32x4*)(src + f);
#pragma unroll
      for (int j = 0; j < 4; ++j) {
        const int n = n0 + j;
        const int byte = n * 128 + ((2 * k) ^ (((n >> 2) & 7) << 4));
        lds[byte >> 1] = f2bf(v[j]);
      }
    }
    __syncthreads();
    for (int it = 0; it < 8; ++it) {
      const int q = (it * 256 + tid) * 8;
      const int n = q >> 7, r = q & 127;
      const int srcoff = (r ^ ((n & 7) << 4)) ^ (((n >> 2) & 7) << 4);
      *(unsigned long long*)(Gs + off + q) =
          *(const unsigned long long*)(smem + n * 128 + srcoff);
    }
  } else {
    // ---- K=128 half matrix (Wa2 / Wc2, 64 n-rows per block) ----
    const bool isA = (t <= 2);
    const float* src = (isA ? Wa2 : Wc2) + s * Ht * Ht;
    const int off = isA ? OA2 : OC2;
    const int nhalf = ((t == 2) || (t == 6)) ? 64 : 0;
    for (int it = 0; it < 8; ++it) {
      const int e4 = it * 256 + tid;           // 2048 f32x4 groups
      const int k = e4 >> 4, nl0 = (e4 & 15) * 4;
      const f32x4 v = *(const f32x4*)(src + k * 128 + nhalf + nl0);
#pragma unroll
      for (int j = 0; j < 4; ++j) {
        const int nl = nl0 + j;
        const int byte = nl * 256 + ((2 * k) ^ (((nl >> 2) & 15) << 4));
        lds[byte >> 1] = f2bf(v[j]);
      }
    }
    __syncthreads();
    for (int it = 0; it < 8; ++it) {
      const int q = (it * 256 + tid) * 8;      // 16KB half image
      const int nl = q >> 8, r = q & 255;
      const int srcoff = (r ^ ((nl & 7) << 4)) ^ (((nl >> 2) & 15) << 4);
      *(unsigned long long*)(Gs + off + (nhalf + nl) * 256 + r) =
          *(const unsigned long long*)(smem + nl * 256 + srcoff);
    }
  }
}

__device__ __forceinline__ bf16x8 wrd(const char* base, int srw, int n, int c,
                                      int lg, int msw) {
  return *(const bf16x8*)(base + n * srw + (((c) + lg * 16) ^ msw));
}

// store tanh(acc)+bias with b2 pre-doubled, in registers
__device__ __forceinline__ void storeh(char* hw, int msw, int lg, int t,
                                       const f32x4 acc, const f32x4 b2) {
  const unsigned lo = cvtpk(tanh_fb(acc[0], b2[0]), tanh_fb(acc[1], b2[1]));
  const unsigned hi = cvtpk(tanh_fb(acc[2], b2[2]), tanh_fb(acc[3], b2[3]));
  *(unsigned long long*)(hw + ((32 * t + 8 * lg) ^ msw)) =
      (unsigned long long)lo | ((unsigned long long)hi << 32);
}

// ---- one 64-row tile, actor role (biases in registers) ----
__device__ __forceinline__ void tile_actor(
    int tbase, int rnext, bool dopref, int& rowcur,
    f32x4& cx0, f32x4& cx1, f32x4& cx2, f32x4& cx3,
    const char* wbuf, char* hw, const float* obs,
    const f32x4 (&b1d)[8], const f32x4 (&b2d)[8], const f32x4 ba3v,
    const float ba316, float* out,
    int m, int lg, int msw, int wm, int cs) {
  union { bf16x8 v; unsigned u[4]; } XB0, XB1;
  XB0.u[0] = cvtpk(cx0[0], cx0[1]); XB0.u[1] = cvtpk(cx0[2], cx0[3]);
  XB0.u[2] = cvtpk(cx1[0], cx1[1]); XB0.u[3] = cvtpk(cx1[2], cx1[3]);
  XB1.u[0] = cvtpk(cx2[0], cx2[1]); XB1.u[1] = cvtpk(cx2[2], cx2[3]);
  XB1.u[2] = cvtpk(cx3[0], cx3[1]); XB1.u[3] = cvtpk(cx3[2], cx3[3]);
  const int myrow = rowcur;
  if (dopref) {  // next tile's obs: in flight across this tile's compute
    const float* ap = obs + rnext * Dt + lg * 8;
    cx0 = *(const f32x4*)(ap);      cx1 = *(const f32x4*)(ap + 4);
    cx2 = *(const f32x4*)(ap + 32); cx3 = *(const f32x4*)(ap + 36);
  }
  rowcur = rnext;
#pragma unroll
  for (int nt = 0; nt < 8; ++nt) {
    const bf16x8 a0 = wrd(wbuf, 128, nt * 16 + m, 0, lg, msw);
    const bf16x8 a1 = wrd(wbuf, 128, nt * 16 + m, 64, lg, msw);
    f32x4 acc = {0.f, 0.f, 0.f, 0.f};
    acc = MFMA(a0, XB0.v, acc);
    acc = MFMA(a1, XB1.v, acc);
    storeh(hw, msw, lg, nt, acc, b1d[nt]);
  }
  LGKM0();
  const bf16x8 h0 = *(const bf16x8*)(hw + ((0   + 16 * lg) ^ msw));
  const bf16x8 h1 = *(const bf16x8*)(hw + ((64  + 16 * lg) ^ msw));
  const bf16x8 h2 = *(const bf16x8*)(hw + ((128 + 16 * lg) ^ msw));
  const bf16x8 h3 = *(const bf16x8*)(hw + ((192 + 16 * lg) ^ msw));
#pragma unroll
  for (int nt = 0; nt < 8; ++nt) {
    const int n = nt * 16 + m;
    const bf16x8 w0 = wrd(wbuf + 16384, 256, n, 0, lg, msw);
    const bf16x8 w1 = wrd(wbuf + 16384, 256, n, 64, lg, msw);
    const bf16x8 w2 = wrd(wbuf + 16384, 256, n, 128, lg, msw);
    const bf16x8 w3 = wrd(wbuf + 16384, 256, n, 192, lg, msw);
    f32x4 acc = {0.f, 0.f, 0.f, 0.f};
    acc = MFMA(w0, h0, acc); acc = MFMA(w1, h1, acc);
    acc = MFMA(w2, h2, acc); acc = MFMA(w3, h3, acc);
    storeh(hw, msw, lg, nt, acc, b2d[nt]);
  }
  LGKM0();
  const bf16x8 H0 = *(const bf16x8*)(hw + ((0   + 16 * lg) ^ msw));
  const bf16x8 H1 = *(const bf16x8*)(hw + ((64  + 16 * lg) ^ msw));
  const bf16x8 H2 = *(const bf16x8*)(hw + ((128 + 16 * lg) ^ msw));
  const bf16x8 H3 = *(const bf16x8*)(hw + ((192 + 16 * lg) ^ msw));
  const char* W3 = wbuf + 49152;
  const bf16x8 e0 = wrd(W3, 256, m, 0, lg, msw);
  const bf16x8 e1 = wrd(W3, 256, m, 64, lg, msw);
  const bf16x8 e2 = wrd(W3, 256, m, 128, lg, msw);
  const bf16x8 e3 = wrd(W3, 256, m, 192, lg, msw);
  const bf16x8 f0 = wrd(W3, 256, 16 + m, 0, lg, msw);
  const bf16x8 f1 = wrd(W3, 256, 16 + m, 64, lg, msw);
  const bf16x8 f2 = wrd(W3, 256, 16 + m, 128, lg, msw);
  const bf16x8 f3 = wrd(W3, 256, 16 + m, 192, lg, msw);
  f32x4 p0 = {0.f, 0.f, 0.f, 0.f}, p1 = {0.f, 0.f, 0.f, 0.f};
  p0 = MFMA(e0, H0, p0); p0 = MFMA(e1, H1, p0);
  p0 = MFMA(e2, H2, p0); p0 = MFMA(e3, H3, p0);
  p1 = MFMA(f0, H0, p1); p1 = MFMA(f1, H1, p1);
  p1 = MFMA(f2, H2, p1); p1 = MFMA(f3, H3, p1);
  if (tbase + wm < cs) {
    float* orow = out + myrow * At;
#pragma unroll
    for (int i = 0; i < 4; ++i)                 // n = 4lg+i in 0..15
      orow[4 * lg + i] = p0[i] + ba3v[i];
    if (lg == 0) orow[16] = p1[0] + ba316;      // n = 16
  }
}

// ---- one 64-row tile, critic role (biases/Wc3 in registers) ----
__device__ __forceinline__ void tile_critic(
    int tbase, int rnext, bool dopref, int& rowcur,
    f32x4& cx0, f32x4& cx1, f32x4& cx2, f32x4& cx3,
    const char* wbuf, char* hw, const float* obs,
    const f32x4 (&b1d)[8], const f32x4 (&b2d)[8], const f32x4 (&wv)[8],
    const float bc3s, float* out,
    int m, int lg, int msw, int wm, int cs, int lane) {
  union { bf16x8 v; unsigned u[4]; } XB0, XB1;
  XB0.u[0] = cvtpk(cx0[0], cx0[1]); XB0.u[1] = cvtpk(cx0[2], cx0[3]);
  XB0.u[2] = cvtpk(cx1[0], cx1[1]); XB0.u[3] = cvtpk(cx1[2], cx1[3]);
  XB1.u[0] = cvtpk(cx2[0], cx2[1]); XB1.u[1] = cvtpk(cx2[2], cx2[3]);
  XB1.u[2] = cvtpk(cx3[0], cx3[1]); XB1.u[3] = cvtpk(cx3[2], cx3[3]);
  const int myrow = rowcur;
  if (dopref) {
    const float* ap = obs + rnext * Dt + lg * 8;
    cx0 = *(const f32x4*)(ap);      cx1 = *(const f32x4*)(ap + 4);
    cx2 = *(const f32x4*)(ap + 32); cx3 = *(const f32x4*)(ap + 36);
  }
  rowcur = rnext;
#pragma unroll
  for (int nt = 0; nt < 8; ++nt) {
    const bf16x8 a0 = wrd(wbuf, 128, nt * 16 + m, 0, lg, msw);
    const bf16x8 a1 = wrd(wbuf, 128, nt * 16 + m, 64, lg, msw);
    f32x4 acc = {0.f, 0.f, 0.f, 0.f};
    acc = MFMA(a0, XB0.v, acc);
    acc = MFMA(a1, XB1.v, acc);
    storeh(hw, msw, lg, nt, acc, b1d[nt]);
  }
  LGKM0();
  const bf16x8 h0 = *(const bf16x8*)(hw + ((0   + 16 * lg) ^ msw));
  const bf16x8 h1 = *(const bf16x8*)(hw + ((64  + 16 * lg) ^ msw));
  const bf16x8 h2 = *(const bf16x8*)(hw + ((128 + 16 * lg) ^ msw));
  const bf16x8 h3 = *(const bf16x8*)(hw + ((192 + 16 * lg) ^ msw));
  float vp = 0.f;
#pragma unroll
  for (int nt = 0; nt < 8; ++nt) {
    const int n = nt * 16 + m;
    const bf16x8 w0 = wrd(wbuf + 16384, 256, n, 0, lg, msw);
    const bf16x8 w1 = wrd(wbuf + 16384, 256, n, 64, lg, msw);
    const bf16x8 w2 = wrd(wbuf + 16384, 256, n, 128, lg, msw);
    const bf16x8 w3 = wrd(wbuf + 16384, 256, n, 192, lg, msw);
    f32x4 acc = {0.f, 0.f, 0.f, 0.f};
    acc = MFMA(w0, h0, acc); acc = MFMA(w1, h1, acc);
    acc = MFMA(w2, h2, acc); acc = MFMA(w3, h3, acc);
#pragma unroll
    for (int i = 0; i < 4; ++i)
      vp = __builtin_fmaf(tanh_fb(acc[i], b2d[nt][i]), wv[nt][i], vp);
  }
  vp += __shfl_xor(vp, 16);
  vp += __shfl_xor(vp, 32);
  if (lane < 16 && (tbase + wm < cs)) out[Bt * At + myrow] = vp + bc3s;
}

// ---------- dispatch 3: persistent per-(skill,role) blocks; staged once (R9) ----------
__global__ __launch_bounds__(256, 2) void k_main(
    const float* __restrict__ obs,
    const float* __restrict__ ba1, const float* __restrict__ ba2,
    const float* __restrict__ ba3, const float* __restrict__ bc1,
    const float* __restrict__ bc2, const float* __restrict__ Wc3,
    const float* __restrict__ bc3,
    const int* __restrict__ cnt, const unsigned short* __restrict__ perm,
    const char* __restrict__ G, float* __restrict__ out) {
  __shared__ __align__(16) char wbuf[57344];  // L1@0 16K | L2@16K 32K | L3@48K 8K
  __shared__ __align__(16) char hbuf[16384];  // 64 rows x 256B, wave-private rows

  const int tid = threadIdx.x;
  const int wave = tid >> 6, lane = tid & 63;
  const int m = lane & 15, lg = lane >> 4;
  const bool actor = (blockIdx.x == 0);
  const int s = blockIdx.y, idx = blockIdx.z;
  const char* Gs = G + s * SKB;
  const int wm = wave * 16 + m;

  // perm for this block's (up to 3) tiles: no cnt dependency -> issue first
  const unsigned short* pb = perm + s * Bt;
  int r0 = pb[idx * 64 + wm];
  int r1 = pb[(idx + 16) * 64 + wm];
  int r2 = pb[(idx + 32) * 64 + wm];
  const int cs = cnt[s];

  // stage all weights ONCE
  if (actor) {
    stageW(Gs + OA1, wbuf, 16384, wave, lane);
    stageW(Gs + OA2, wbuf + 16384, 32768, wave, lane);
    stageW(Gs + OA3, wbuf + 49152, 8192, wave, lane);
  } else {
    stageW(Gs + OC1, wbuf, 16384, wave, lane);
    stageW(Gs + OC2, wbuf + 16384, 32768, wave, lane);
  }

  r0 = min(r0, Bt - 1); r1 = min(r1, Bt - 1); r2 = min(r2, Bt - 1);
  const int ntl = (cs + 63) >> 6;

  f32x4 cx0, cx1, cx2, cx3;
  {
    const float* ap = obs + r0 * Dt + lg * 8;
    cx0 = *(const f32x4*)(ap);      cx1 = *(const f32x4*)(ap + 4);
    cx2 = *(const f32x4*)(ap + 32); cx3 = *(const f32x4*)(ap + 36);
  }

  char* hw = hbuf + wm * 256;
  const int msw = (m & 7) << 4;
  int rowcur = r0;

  if (actor) {
    // preload all biases into registers (pre-doubled) BEFORE the barrier
    f32x4 b1d[8], b2d[8];
#pragma unroll
    for (int nt = 0; nt < 8; ++nt) {
      const f32x4 t1 = *(const f32x4*)(ba1 + s * Ht + nt * 16 + lg * 4);
      const f32x4 t2 = *(const f32x4*)(ba2 + s * Ht + nt * 16 + lg * 4);
      b1d[nt] = t1 + t1;
      b2d[nt] = t2 + t2;
    }
    const f32x4 ba3v = *(const f32x4*)(ba3 + s * At + 4 * lg);
    const float ba316 = ba3[s * At + 16];
    __syncthreads();                     // weights + all reg preloads drained
    tile_actor(idx * 64, r1, true, rowcur, cx0, cx1, cx2, cx3,
               wbuf, hw, obs, b1d, b2d, ba3v, ba316, out, m, lg, msw, wm, cs);
    if (idx + 16 < ntl)
      tile_actor((idx + 16) * 64, r2, true, rowcur, cx0, cx1, cx2, cx3,
                 wbuf, hw, obs, b1d, b2d, ba3v, ba316, out, m, lg, msw, wm, cs);
    if (idx + 32 < ntl)
      tile_actor((idx + 32) * 64, r2, false, rowcur, cx0, cx1, cx2, cx3,
                 wbuf, hw, obs, b1d, b2d, ba3v, ba316, out, m, lg, msw, wm, cs);
  } else {
    f32x4 b1d[8], b2d[8], wv[8];
#pragma unroll
    for (int nt = 0; nt < 8; ++nt) {
      const f32x4 t1 = *(const f32x4*)(bc1 + s * Ht + nt * 16 + lg * 4);
      const f32x4 t2 = *(const f32x4*)(bc2 + s * Ht + nt * 16 + lg * 4);
      wv[nt] = *(const f32x4*)(Wc3 + s * Ht + nt * 16 + lg * 4);
      b1d[nt] = t1 + t1;
      b2d[nt] = t2 + t2;
    }
    const float bc3s = bc3[s];
    __syncthreads();
    tile_critic(idx * 64, r1, true, rowcur, cx0, cx1, cx2, cx3,
                wbuf, hw, obs, b1d, b2d, wv, bc3s, out, m, lg, msw, wm, cs, lane);
    if (idx + 16 < ntl)
      tile_critic((idx + 16) * 64, r2, true, rowcur, cx0, cx1, cx2, cx3,
                  wbuf, hw, obs, b1d, b2d, wv, bc3s, out, m, lg, msw, wm, cs, lane);
    if (idx + 32 < ntl)
      tile_critic((idx + 32) * 64, r2, false, rowcur, cx0, cx1, cx2, cx3,
                  wbuf, hw, obs, b1d, b2d, wv, bc3s, out, m, lg, msw, wm, cs, lane);
  }
}

extern "C" void kernel_launch(void* const* d_in, const int* in_sizes, int n_in,
                              void* d_out, int out_size, void* d_ws, size_t ws_size,
                              hipStream_t stream) {
  const float* obs = (const float*)d_in[0];
  const int* sid   = (const int*)d_in[1];
  const float* Wa1 = (const float*)d_in[2];
  const float* ba1 = (const float*)d_in[3];
  const float* Wa2 = (const float*)d_in[4];
  const float* ba2 = (const float*)d_in[5];
  const float* Wa3 = (const float*)d_in[6];
  const float* ba3 = (const float*)d_in[7];
  const float* Wc1 = (const float*)d_in[8];
  const float* bc1 = (const float*)d_in[9];
  const float* Wc2 = (const float*)d_in[10];
  const float* bc2 = (const float*)d_in[11];
  const float* Wc3 = (const float*)d_in[12];
  const float* bc3 = (const float*)d_in[13];
  float* out = (float*)d_out;
  char* ws = (char*)d_ws;

  int* cnt = (int*)(ws + CNT_OFF);
  unsigned short* perm = (unsigned short*)(ws + PERM_OFF);
  char* G = ws + WB_OFF;

  hipMemsetAsync(cnt, 0, St * sizeof(int), stream);
  k_fused<<<dim3(240), dim3(256), 0, stream>>>(sid, perm, cnt, Wa1, Wa2, Wa3, Wc1, Wc2, G);
  k_main<<<dim3(2, 16, 16), dim3(256), 0, stream>>>(
      obs, ba1, ba2, ba3, bc1, bc2, Wc3, bc3, cnt, perm, G, out);
}